// Round 8
// baseline (77.718 us; speedup 1.0000x reference)
//
#include <hip/hip_runtime.h>
#include <stdint.h>

// Problem constants (fixed by reference: N=64, I=8192, D=128, K=16)
#define NB 64
#define NI 8192
#define ND 128
#define NK 16
#define SEG (NK * ND)                 // 2048 elems per batch's output
#define OUT_ELEMS (NB * SEG)          // 131072
#define MAPPED_NEG_INF 0x007FFFFFu    // map(-inf)

// ---- Path A: PPB=1024, 1024-thread blocks, 512 blocks (2/CU, 32 waves/CU),
//      fused last-block-per-batch reduce (rocPRIM pattern). ----
#define PPB_A 1024
#define BPB_A (NI / PPB_A)            // 8 partials per batch
#define GRID_A (NB * BPB_A)           // 512
#define CNT_OFF ((size_t)GRID_A * SEG)              // u32 index of counters in ws
#define WS_NEEDED (((size_t)GRID_A * SEG + NB) * 4) // 4 MB + 256 B

typedef float f4 __attribute__((ext_vector_type(4)));
typedef uint32_t u4 __attribute__((ext_vector_type(4)));

// Order-preserving float->uint map: max(float) == umax(mapped)
__device__ __forceinline__ uint32_t map_f32(float f) {
    uint32_t b = __float_as_uint(f);
    return b ^ ((uint32_t)((int32_t)b >> 31) | 0x80000000u);
}
__device__ __forceinline__ uint32_t unmap_u32(uint32_t m) {
    return (m & 0x80000000u) ? (m ^ 0x80000000u) : ~m;
}

// ================= Path A =================
__global__ __launch_bounds__(1024, 8) void seg_fused(
        const float* __restrict__ x,
        const int* __restrict__ ci,
        uint32_t* __restrict__ ws,
        uint32_t* __restrict__ out) {
    __shared__ uint32_t loc[SEG];     // 8 KB, swizzled: (c,d) -> c*128 + (d&3)*32 + (d>>2)
    __shared__ int cidx[PPB_A];       // 4 KB
    __shared__ int sIsLast;

    const int t = threadIdx.x;
    const int b = blockIdx.x;
    const int batch = b >> 3;                       // / BPB_A
    const int row0 = batch * NI + (b & (BPB_A - 1)) * PPB_A;

    // init LDS accumulator (2 elems/thread)
    for (int i = t; i < SEG; i += 1024) loc[i] = MAPPED_NEG_INF;
    // vectorized index staging, rebased to this batch
    if (t < PPB_A / 4) {
        int4 c = ((const int4*)(ci + row0))[t];
        const int base = batch * NK;
        c.x -= base; c.y -= base; c.z -= base; c.w -= base;
        ((int4*)cidx)[t] = c;
    }
    __syncthreads();

    const int lane32 = t & 31;
    const int rsub = t >> 5;          // 0..31 -> 32 rows per iteration
    const f4* xrow = (const f4*)(x + (size_t)row0 * ND) + lane32;

    // Atomic bank = lane32 for all four updates -> conflict-free per half-wave.
    #pragma unroll 2
    for (int it = 0; it < PPB_A / 32; ++it) {
        const int i = it * 32 + rsub;
        const int c = cidx[i];
        f4 v = xrow[(size_t)i * (ND / 4)];
        uint32_t* lp = &loc[(c << 7) + lane32];
        atomicMax(&lp[0],  map_f32(v.x));
        atomicMax(&lp[32], map_f32(v.y));
        atomicMax(&lp[64], map_f32(v.z));
        atomicMax(&lp[96], map_f32(v.w));
    }
    __syncthreads();

    // Coalesced vector store of un-swizzled partial (overwrites poison; no init pass).
    // Threads 0..511 write elems o=4t..4t+3: same c, li = c*128 + {0,32,64,96} + (t&31).
    if (t < SEG / 4) {
        const int c = t >> 5;
        const int dq = t & 31;
        u4 r;
        r.x = loc[(c << 7) + dq];
        r.y = loc[(c << 7) + 32 + dq];
        r.z = loc[(c << 7) + 64 + dq];
        r.w = loc[(c << 7) + 96 + dq];
        ((u4*)(ws + (size_t)b * SEG))[t] = r;
    }
    __syncthreads();   // all partial stores issued (barrier drains vmcnt)

    // Publish: device-scope release, then bump this batch's arrival counter.
    if (t == 0) {
        __threadfence();                                   // release partial stores
        unsigned old = atomicAdd(ws + CNT_OFF + batch, 1u);
        sIsLast = (old == BPB_A - 1);
        if (sIsLast) __threadfence();                      // acquire before reading partials
    }
    __syncthreads();

    // Last block of this batch reduces its 8 partials -> out. Other blocks exit.
    if (sIsLast && t < SEG / 4) {
        const u4* p = (const u4*)(ws + (size_t)batch * BPB_A * SEG) + t;
        u4 m;
        m.x = m.y = m.z = m.w = MAPPED_NEG_INF;
        #pragma unroll
        for (int j = 0; j < BPB_A; ++j) {
            u4 v = p[(size_t)j * (SEG / 4)];
            m.x = v.x > m.x ? v.x : m.x;
            m.y = v.y > m.y ? v.y : m.y;
            m.z = v.z > m.z ? v.z : m.z;
            m.w = v.w > m.w ? v.w : m.w;
        }
        u4 r;
        r.x = unmap_u32(m.x); r.y = unmap_u32(m.y);
        r.z = unmap_u32(m.z); r.w = unmap_u32(m.w);
        ((u4*)(out + (size_t)batch * SEG))[t] = r;
    }
}

// ================= Path B (fallback: 3 kernels, global atomics) =================
#define PPB_B 256
#define BPB_B (NI / PPB_B)

__global__ __launch_bounds__(256) void seg_init(uint32_t* __restrict__ out) {
    int idx = blockIdx.x * 256 + threadIdx.x;
    out[idx] = MAPPED_NEG_INF;
}

__global__ __launch_bounds__(256, 8) void seg_max_kernel(
        const float* __restrict__ x,
        const int* __restrict__ ci,
        uint32_t* __restrict__ out) {
    __shared__ uint32_t loc[SEG];
    __shared__ int cidx[PPB_B];

    const int t = threadIdx.x;
    const int b = blockIdx.x;
    const int batch = b >> 5;
    const int row0 = batch * NI + (b & (BPB_B - 1)) * PPB_B;

    for (int i = t; i < SEG; i += 256) loc[i] = MAPPED_NEG_INF;
    cidx[t] = ci[row0 + t] - batch * NK;
    __syncthreads();

    const int lane32 = t & 31;
    const int rsub = t >> 5;
    const f4* xrow = (const f4*)(x + (size_t)row0 * ND) + lane32;

    for (int it = 0; it < PPB_B / 8; ++it) {
        const int i = it * 8 + rsub;
        const int c = cidx[i];
        f4 v = xrow[(size_t)i * (ND / 4)];
        uint32_t* lp = &loc[(c << 7) + lane32];
        atomicMax(&lp[0],  map_f32(v.x));
        atomicMax(&lp[32], map_f32(v.y));
        atomicMax(&lp[64], map_f32(v.z));
        atomicMax(&lp[96], map_f32(v.w));
    }
    __syncthreads();

    uint32_t* ob = out + (size_t)batch * SEG;
    for (int o = t; o < SEG; o += 256) {
        const int c = o >> 7;
        const int d = o & 127;
        uint32_t v = loc[(c << 7) + ((d & 3) << 5) + (d >> 2)];
        if (v != MAPPED_NEG_INF) atomicMax(&ob[o], v);
    }
}

__global__ __launch_bounds__(256) void seg_decode(uint32_t* __restrict__ out) {
    int idx = blockIdx.x * 256 + threadIdx.x;
    out[idx] = unmap_u32(out[idx]);
}

extern "C" void kernel_launch(void* const* d_in, const int* in_sizes, int n_in,
                              void* d_out, int out_size, void* d_ws, size_t ws_size,
                              hipStream_t stream) {
    const float* x = (const float*)d_in[0];
    const int* ci = (const int*)d_in[1];
    uint32_t* out = (uint32_t*)d_out;

    if (ws_size >= WS_NEEDED) {
        uint32_t* ws = (uint32_t*)d_ws;
        // zero the 64 per-batch arrival counters (graph-capture-legal async memset)
        hipMemsetAsync((char*)d_ws + CNT_OFF * 4, 0, NB * 4, stream);
        seg_fused<<<GRID_A, 1024, 0, stream>>>(x, ci, ws, out);
    } else {
        seg_init<<<OUT_ELEMS / 256, 256, 0, stream>>>(out);
        seg_max_kernel<<<NB * BPB_B, 256, 0, stream>>>(x, ci, out);
        seg_decode<<<OUT_ELEMS / 256, 256, 0, stream>>>(out);
    }
}

// Round 9
// 47.345 us; speedup vs baseline: 1.6415x; 1.6415x over previous
//
#include <hip/hip_runtime.h>
#include <stdint.h>

// Problem constants (fixed by reference: N=64, I=8192, D=128, K=16)
#define NB 64
#define NI 8192
#define ND 128
#define NK 16
#define SEG (NK * ND)                 // 2048 elems per batch's output
#define OUT_ELEMS (NB * SEG)          // 131072
#define MAPPED_NEG_INF 0x007FFFFFu    // map(-inf)

// ---- Path A: PPB=1024, 1024-thread blocks, 512 blocks (2/CU, 32 waves/CU) ----
// R6-proven best: partial kernel streams at 6.27 TB/s (copy ceiling).
#define PPB_A 1024
#define BPB_A (NI / PPB_A)            // 8 partials per batch
#define GRID_A (NB * BPB_A)           // 512
#define WS_NEEDED ((size_t)GRID_A * SEG * 4)  // 4 MB

typedef float f4 __attribute__((ext_vector_type(4)));
typedef uint32_t u4 __attribute__((ext_vector_type(4)));

// Order-preserving float->uint map: max(float) == umax(mapped)
__device__ __forceinline__ uint32_t map_f32(float f) {
    uint32_t b = __float_as_uint(f);
    return b ^ ((uint32_t)((int32_t)b >> 31) | 0x80000000u);
}
__device__ __forceinline__ uint32_t unmap_u32(uint32_t m) {
    return (m & 0x80000000u) ? (m ^ 0x80000000u) : ~m;
}

// ================= Path A =================
__global__ __launch_bounds__(1024, 8) void seg_partial(
        const float* __restrict__ x,
        const int* __restrict__ ci,
        uint32_t* __restrict__ ws) {
    __shared__ uint32_t loc[SEG];     // 8 KB, swizzled: (c,d) -> c*128 + (d&3)*32 + (d>>2)
    __shared__ int cidx[PPB_A];       // 4 KB

    const int t = threadIdx.x;
    const int b = blockIdx.x;
    const int batch = b >> 3;                       // / BPB_A
    const int row0 = batch * NI + (b & (BPB_A - 1)) * PPB_A;

    // init LDS accumulator (2 elems/thread)
    for (int i = t; i < SEG; i += 1024) loc[i] = MAPPED_NEG_INF;
    // vectorized index staging, rebased to this batch
    if (t < PPB_A / 4) {
        int4 c = ((const int4*)(ci + row0))[t];
        const int base = batch * NK;
        c.x -= base; c.y -= base; c.z -= base; c.w -= base;
        ((int4*)cidx)[t] = c;
    }
    __syncthreads();

    const int lane32 = t & 31;
    const int rsub = t >> 5;          // 0..31 -> 32 rows per iteration
    const f4* xrow = (const f4*)(x + (size_t)row0 * ND) + lane32;

    // Atomic bank = lane32 for all four updates -> conflict-free per half-wave.
    #pragma unroll 2
    for (int it = 0; it < PPB_A / 32; ++it) {
        const int i = it * 32 + rsub;
        const int c = cidx[i];
        f4 v = xrow[(size_t)i * (ND / 4)];
        uint32_t* lp = &loc[(c << 7) + lane32];
        atomicMax(&lp[0],  map_f32(v.x));
        atomicMax(&lp[32], map_f32(v.y));
        atomicMax(&lp[64], map_f32(v.z));
        atomicMax(&lp[96], map_f32(v.w));
    }
    __syncthreads();

    // Coalesced vector store of un-swizzled partials (overwrites poison; no init pass).
    // Threads 0..511 write elems o=4t..4t+3: same c, li = c*128 + {0,32,64,96} + (t&31).
    if (t < SEG / 4) {
        const int c = t >> 5;
        const int dq = t & 31;
        u4 r;
        r.x = loc[(c << 7) + dq];
        r.y = loc[(c << 7) + 32 + dq];
        r.z = loc[(c << 7) + 64 + dq];
        r.w = loc[(c << 7) + 96 + dq];
        ((u4*)(ws + (size_t)b * SEG))[t] = r;
    }
}

__global__ __launch_bounds__(256) void seg_reduce(
        const uint32_t* __restrict__ ws,
        uint32_t* __restrict__ out) {
    const int idx = blockIdx.x * 256 + threadIdx.x;   // 0..OUT_ELEMS/4-1
    const int batch = idx >> 9;                       // / (SEG/4)
    const int o4 = idx & (SEG / 4 - 1);
    const u4* p = (const u4*)(ws + (size_t)batch * BPB_A * SEG) + o4;
    u4 m;
    m.x = m.y = m.z = m.w = MAPPED_NEG_INF;
    #pragma unroll
    for (int j = 0; j < BPB_A; ++j) {
        u4 v = p[(size_t)j * (SEG / 4)];
        m.x = v.x > m.x ? v.x : m.x;
        m.y = v.y > m.y ? v.y : m.y;
        m.z = v.z > m.z ? v.z : m.z;
        m.w = v.w > m.w ? v.w : m.w;
    }
    u4 r;
    r.x = unmap_u32(m.x); r.y = unmap_u32(m.y);
    r.z = unmap_u32(m.z); r.w = unmap_u32(m.w);
    ((u4*)out)[idx] = r;
}

// ================= Path B (fallback: 3 kernels, global atomics) =================
#define PPB_B 256
#define BPB_B (NI / PPB_B)

__global__ __launch_bounds__(256) void seg_init(uint32_t* __restrict__ out) {
    int idx = blockIdx.x * 256 + threadIdx.x;
    out[idx] = MAPPED_NEG_INF;
}

__global__ __launch_bounds__(256, 8) void seg_max_kernel(
        const float* __restrict__ x,
        const int* __restrict__ ci,
        uint32_t* __restrict__ out) {
    __shared__ uint32_t loc[SEG];
    __shared__ int cidx[PPB_B];

    const int t = threadIdx.x;
    const int b = blockIdx.x;
    const int batch = b >> 5;
    const int row0 = batch * NI + (b & (BPB_B - 1)) * PPB_B;

    for (int i = t; i < SEG; i += 256) loc[i] = MAPPED_NEG_INF;
    cidx[t] = ci[row0 + t] - batch * NK;
    __syncthreads();

    const int lane32 = t & 31;
    const int rsub = t >> 5;
    const f4* xrow = (const f4*)(x + (size_t)row0 * ND) + lane32;

    for (int it = 0; it < PPB_B / 8; ++it) {
        const int i = it * 8 + rsub;
        const int c = cidx[i];
        f4 v = xrow[(size_t)i * (ND / 4)];
        uint32_t* lp = &loc[(c << 7) + lane32];
        atomicMax(&lp[0],  map_f32(v.x));
        atomicMax(&lp[32], map_f32(v.y));
        atomicMax(&lp[64], map_f32(v.z));
        atomicMax(&lp[96], map_f32(v.w));
    }
    __syncthreads();

    uint32_t* ob = out + (size_t)batch * SEG;
    for (int o = t; o < SEG; o += 256) {
        const int c = o >> 7;
        const int d = o & 127;
        uint32_t v = loc[(c << 7) + ((d & 3) << 5) + (d >> 2)];
        if (v != MAPPED_NEG_INF) atomicMax(&ob[o], v);
    }
}

__global__ __launch_bounds__(256) void seg_decode(uint32_t* __restrict__ out) {
    int idx = blockIdx.x * 256 + threadIdx.x;
    out[idx] = unmap_u32(out[idx]);
}

extern "C" void kernel_launch(void* const* d_in, const int* in_sizes, int n_in,
                              void* d_out, int out_size, void* d_ws, size_t ws_size,
                              hipStream_t stream) {
    const float* x = (const float*)d_in[0];
    const int* ci = (const int*)d_in[1];
    uint32_t* out = (uint32_t*)d_out;

    if (ws_size >= WS_NEEDED) {
        uint32_t* ws = (uint32_t*)d_ws;
        seg_partial<<<GRID_A, 1024, 0, stream>>>(x, ci, ws);
        seg_reduce<<<OUT_ELEMS / 4 / 256, 256, 0, stream>>>(ws, out);
    } else {
        seg_init<<<OUT_ELEMS / 256, 256, 0, stream>>>(out);
        seg_max_kernel<<<NB * BPB_B, 256, 0, stream>>>(x, ci, out);
        seg_decode<<<OUT_ELEMS / 256, 256, 0, stream>>>(out);
    }
}